// Round 5
// baseline (664.683 us; speedup 1.0000x reference)
//
#include <hip/hip_runtime.h>
#include <stdint.h>
#include <stddef.h>

#define TB    4096
#define NDIM  1024
#define NH    16
#define KPROJ 256
#define DH    64
#define NBH   64

typedef _Float16 f16;
typedef _Float16 f16x8 __attribute__((ext_vector_type(8)));
typedef float    f32x4 __attribute__((ext_vector_type(4)));

__device__ __forceinline__ void glds16(const f16* g, f16* l) {
  __builtin_amdgcn_global_load_lds((const __attribute__((address_space(1))) void*)g,
                                   (__attribute__((address_space(3))) void*)l, 16, 0, 0);
}

// ---------------------------------------------------------------------------
// fp32 -> fp16 elementwise (X)
// ---------------------------------------------------------------------------
__launch_bounds__(256)
__global__ void cvt_x(const float* __restrict__ in, f16* __restrict__ out) {
  size_t i = ((size_t)blockIdx.x * 256 + threadIdx.x) * 8;
  float4 v0 = *(const float4*)(in + i);
  float4 v1 = *(const float4*)(in + i + 4);
  union { f16 h[8]; uint4 u; } pk;
  pk.h[0] = (f16)v0.x; pk.h[1] = (f16)v0.y; pk.h[2] = (f16)v0.z; pk.h[3] = (f16)v0.w;
  pk.h[4] = (f16)v1.x; pk.h[5] = (f16)v1.y; pk.h[6] = (f16)v1.z; pk.h[7] = (f16)v1.w;
  *(uint4*)(out + i) = pk.u;
}

// ---------------------------------------------------------------------------
// fp32 [R][C] -> fp16 transposed [C][R]
// ---------------------------------------------------------------------------
__launch_bounds__(256)
__global__ void cvt_t(const float* __restrict__ in, f16* __restrict__ out, int R, int C) {
  __shared__ __align__(16) f16 s[64][72];
  const int tid = threadIdx.x;
  const int c0 = blockIdx.x * 64, r0 = blockIdx.y * 64;
#pragma unroll
  for (int it = 0; it < 4; ++it) {
    int chunk = it * 256 + tid;
    int r_l = chunk >> 4, c4 = (chunk & 15) * 4;
    float4 v = *(const float4*)(in + (size_t)(r0 + r_l) * C + c0 + c4);
    s[c4 + 0][r_l] = (f16)v.x; s[c4 + 1][r_l] = (f16)v.y;
    s[c4 + 2][r_l] = (f16)v.z; s[c4 + 3][r_l] = (f16)v.w;
  }
  __syncthreads();
#pragma unroll
  for (int it = 0; it < 2; ++it) {
    int chunk = it * 256 + tid;
    int c_l = chunk >> 3, rc = (chunk & 7) * 8;
    *(uint4*)(out + (size_t)(c0 + c_l) * R + r0 + rc) = *(const uint4*)&s[c_l][rc];
  }
}

// ---------------------------------------------------------------------------
// Stage 1: qkv = Xh @ Wt^T  (M=16384, N=3072, K=1024) fp16 MFMA, 128x128x32.
// Epilogue: C tile -> LDS [f][m] -> 16B full-sector stores into q/k/v [bh][d][t].
// ---------------------------------------------------------------------------
__launch_bounds__(256)
__global__ void k_qkv(const f16* __restrict__ Xh, const f16* __restrict__ Wt,
                      f16* __restrict__ qt, f16* __restrict__ kvt) {
  __shared__ __align__(16) f16 As[128 * 32];
  __shared__ __align__(16) f16 Bs[128 * 32];
  __shared__ __align__(16) f16 Cs[128][136];  // 34 KB, row=f local, col=m local
  const int tid = threadIdx.x;
  const int w = tid >> 6, lane = tid & 63;
  const int quad = lane >> 4, l15 = lane & 15;
  const int bn0 = blockIdx.x * 128, bm0 = blockIdx.y * 128;
  const int wm = (w & 1) * 64, wn = (w >> 1) * 64;
  const int srow = lane >> 2, skc = lane & 3;

  f32x4 acc[4][4];
#pragma unroll
  for (int i = 0; i < 4; ++i)
#pragma unroll
    for (int j = 0; j < 4; ++j) acc[i][j] = (f32x4){0.f, 0.f, 0.f, 0.f};

  const f16* Ag0 = Xh + (size_t)(bm0 + w * 32 + srow) * NDIM + skc * 8;
  const f16* Bg0 = Wt + (size_t)(bn0 + w * 32 + srow) * NDIM + skc * 8;
  f16* Al0 = As + (w * 32) * 32;
  f16* Bl0 = Bs + (w * 32) * 32;

  for (int k0 = 0; k0 < NDIM; k0 += 32) {
    glds16(Ag0 + k0, Al0);
    glds16(Ag0 + (size_t)16 * NDIM + k0, Al0 + 16 * 32);
    glds16(Bg0 + k0, Bl0);
    glds16(Bg0 + (size_t)16 * NDIM + k0, Bl0 + 16 * 32);
    __syncthreads();
    f16x8 a[4], b[4];
#pragma unroll
    for (int i = 0; i < 4; ++i) a[i] = *(const f16x8*)(As + (wm + i * 16 + l15) * 32 + quad * 8);
#pragma unroll
    for (int j = 0; j < 4; ++j) b[j] = *(const f16x8*)(Bs + (wn + j * 16 + l15) * 32 + quad * 8);
#pragma unroll
    for (int i = 0; i < 4; ++i)
#pragma unroll
      for (int j = 0; j < 4; ++j)
        acc[i][j] = __builtin_amdgcn_mfma_f32_16x16x32_f16(a[i], b[j], acc[i][j], 0, 0, 0);
    __syncthreads();
  }

  // C tile -> LDS [f][m] (4 consecutive m per 8B write)
#pragma unroll
  for (int i = 0; i < 4; ++i)
#pragma unroll
    for (int j = 0; j < 4; ++j) {
      union { f16 hh[4]; uint2 u; } pk;
#pragma unroll
      for (int r = 0; r < 4; ++r) pk.hh[r] = (f16)acc[i][j][r];
      *(uint2*)&Cs[wn + j * 16 + l15][wm + i * 16 + quad * 4] = pk.u;
    }
  __syncthreads();

  // each thread streams 64 m (=t) of one f row: 8 x 16B full-sector stores
  const int f_l = tid >> 1, mh = (tid & 1) * 64;
  const int f = bn0 + f_l;
  const int d = f / 48, rem = f - d * 48;
  const int rr = rem >> 4, h = rem & 15;
  f16* base = (rr == 0) ? qt : kvt + (size_t)(rr - 1) * ((size_t)NBH * DH * TB);
  const int bb = bm0 >> 12, tt0 = bm0 & 4095;
  f16* dst = base + ((size_t)((bb * NH + h) * DH + d)) * TB + tt0 + mh;
  const f16* srcp = &Cs[f_l][mh];
#pragma unroll
  for (int kx = 0; kx < 8; ++kx)
    *(uint4*)(dst + kx * 8) = *(const uint4*)(srcp + kx * 8);
}

// ---------------------------------------------------------------------------
// Stage 2: kp/vp = Pt @ kvt^T per (bh, r): M=128(kappa), N=64(d), K=4096(t).
// rv==0 (k): kp [bh][kappa][d];  rv==1 (v): vpT [bh][d][kappa].
// ---------------------------------------------------------------------------
__launch_bounds__(256)
__global__ void k_proj(const f16* __restrict__ Pt, const f16* __restrict__ kvt,
                       f16* __restrict__ kpv) {
  __shared__ __align__(16) f16 As[128 * 32];
  __shared__ __align__(16) f16 Bs[64 * 32];
  const int tid = threadIdx.x;
  const int w = tid >> 6, lane = tid & 63;
  const int quad = lane >> 4, l15 = lane & 15;
  const int km0 = blockIdx.x * 128;
  const int bh = blockIdx.y, rv = blockIdx.z;
  const int srow = lane >> 2, skc = lane & 3;
  const f16* Bbase = kvt + (size_t)(rv * NBH + bh) * DH * TB;  // [d][t]

  f32x4 acc[2][4];
#pragma unroll
  for (int i = 0; i < 2; ++i)
#pragma unroll
    for (int j = 0; j < 4; ++j) acc[i][j] = (f32x4){0.f, 0.f, 0.f, 0.f};

  const f16* Ag0 = Pt + (size_t)(km0 + w * 32 + srow) * TB + skc * 8;
  const f16* Bg0 = Bbase + (size_t)(w * 16 + srow) * TB + skc * 8;
  f16* Al0 = As + (w * 32) * 32;
  f16* Bl0 = Bs + (w * 16) * 32;

  for (int k0 = 0; k0 < TB; k0 += 32) {
    glds16(Ag0 + k0, Al0);
    glds16(Ag0 + (size_t)16 * TB + k0, Al0 + 16 * 32);
    glds16(Bg0 + k0, Bl0);
    __syncthreads();
    f16x8 a[2], b[4];
#pragma unroll
    for (int i = 0; i < 2; ++i) a[i] = *(const f16x8*)(As + (w * 32 + i * 16 + l15) * 32 + quad * 8);
#pragma unroll
    for (int j = 0; j < 4; ++j) b[j] = *(const f16x8*)(Bs + (j * 16 + l15) * 32 + quad * 8);
#pragma unroll
    for (int i = 0; i < 2; ++i)
#pragma unroll
      for (int j = 0; j < 4; ++j)
        acc[i][j] = __builtin_amdgcn_mfma_f32_16x16x32_f16(a[i], b[j], acc[i][j], 0, 0, 0);
    __syncthreads();
  }

  if (rv == 0) {
#pragma unroll
    for (int i = 0; i < 2; ++i) {
      int kap0 = km0 + w * 32 + i * 16 + quad * 4;
#pragma unroll
      for (int j = 0; j < 4; ++j) {
        int d = j * 16 + l15;
#pragma unroll
        for (int r = 0; r < 4; ++r)
          kpv[((size_t)bh * KPROJ + kap0 + r) * DH + d] = (f16)acc[i][j][r];
      }
    }
  } else {
    f16* vpT = kpv + (size_t)NBH * KPROJ * DH;
#pragma unroll
    for (int i = 0; i < 2; ++i) {
      int kap0 = km0 + w * 32 + i * 16 + quad * 4;
#pragma unroll
      for (int j = 0; j < 4; ++j) {
        int d = j * 16 + l15;
        union { f16 hh[4]; uint2 u; } pk;
#pragma unroll
        for (int r = 0; r < 4; ++r) pk.hh[r] = (f16)acc[i][j][r];
        *(uint2*)&vpT[((size_t)bh * DH + d) * KPROJ + kap0] = pk.u;
      }
    }
  }
}

// ---------------------------------------------------------------------------
// Stage 3+4: fused MFMA attention. grid (T/64, 64 bh), 4 waves; wave owns 16
// q-rows. q A-frags via LDS transpose (FIXED: 2-pass loader covers all 64 t);
// S B-frags from global (L2); softmax in C-layout regs; P via wave-private
// LDS; PV B-frags from global; O via LDS (reusing Ps) -> 16B stores.
// ---------------------------------------------------------------------------
__launch_bounds__(256)
__global__ void k_attn(const f16* __restrict__ qt, const f16* __restrict__ kpv,
                       f16* __restrict__ aout) {
  __shared__ __align__(16) f16 Ps[4][16][264];  // 33 KB (P staging, then O staging)
  __shared__ __align__(16) f16 Qs[64][72];      // 9 KB q tile transposed [t][d]
  const int tid = threadIdx.x;
  const int w = tid >> 6, lane = tid & 63;
  const int quad = lane >> 4, l15 = lane & 15;
  const int bh = blockIdx.y;
  const int t0b = blockIdx.x * 64;
  const int b = bh >> 4, h = bh & 15;

  {  // q tile: qt[bh][d][t0b..t0b+64) -> Qs[t][d]; 512 uint4 loads, 2/thread
#pragma unroll
    for (int it = 0; it < 2; ++it) {
      int idx = it * 256 + tid;
      int d_l = idx >> 3, ck = idx & 7;
      uint4 u = *(const uint4*)(qt + ((size_t)bh * DH + d_l) * TB + t0b + ck * 8);
      const f16* hp = (const f16*)&u;
#pragma unroll
      for (int e = 0; e < 8; ++e) Qs[ck * 8 + e][d_l] = hp[e];
    }
  }
  __syncthreads();

  f16x8 aq[2];
#pragma unroll
  for (int ks = 0; ks < 2; ++ks)
    aq[ks] = *(const f16x8*)&Qs[w * 16 + l15][ks * 32 + quad * 8];

  // S: 16 n-tiles of 16 kappa; B-frags from global (L2-resident)
  f32x4 sc[16];
  const f16* kpb = kpv + (size_t)bh * (KPROJ * DH);
#pragma unroll 4
  for (int nt = 0; nt < 16; ++nt) {
    f16x8 b0 = *(const f16x8*)(kpb + (size_t)(nt * 16 + l15) * DH + quad * 8);
    f16x8 b1 = *(const f16x8*)(kpb + (size_t)(nt * 16 + l15) * DH + 32 + quad * 8);
    f32x4 c = (f32x4){0.f, 0.f, 0.f, 0.f};
    c = __builtin_amdgcn_mfma_f32_16x16x32_f16(aq[0], b0, c, 0, 0, 0);
    c = __builtin_amdgcn_mfma_f32_16x16x32_f16(aq[1], b1, c, 0, 0, 0);
    sc[nt] = c;
  }

  // softmax: rows at quad*4+r, cols nt*16+l15
  float mx[4] = {-1e30f, -1e30f, -1e30f, -1e30f};
#pragma unroll
  for (int nt = 0; nt < 16; ++nt)
#pragma unroll
    for (int r = 0; r < 4; ++r) {
      float s = sc[nt][r] * 0.125f;
      sc[nt][r] = s;
      mx[r] = fmaxf(mx[r], s);
    }
#pragma unroll
  for (int r = 0; r < 4; ++r)
#pragma unroll
    for (int off = 1; off < 16; off <<= 1) mx[r] = fmaxf(mx[r], __shfl_xor(mx[r], off));
  float sm[4] = {0.f, 0.f, 0.f, 0.f};
#pragma unroll
  for (int nt = 0; nt < 16; ++nt)
#pragma unroll
    for (int r = 0; r < 4; ++r) {
      float e = __expf(sc[nt][r] - mx[r]);
      sc[nt][r] = e;
      sm[r] += e;
    }
#pragma unroll
  for (int r = 0; r < 4; ++r)
#pragma unroll
    for (int off = 1; off < 16; off <<= 1) sm[r] += __shfl_xor(sm[r], off);

  // P -> LDS (pack lane pairs -> b32, even lanes write)
#pragma unroll
  for (int nt = 0; nt < 16; ++nt)
#pragma unroll
    for (int r = 0; r < 4; ++r) {
      f16 hh = (f16)sc[nt][r];
      uint32_t hb = (uint32_t)__builtin_bit_cast(uint16_t, hh);
      uint32_t nb = (uint32_t)__shfl_xor((int)hb, 1);
      if (!(lane & 1))
        *(uint32_t*)&Ps[w][quad * 4 + r][nt * 16 + l15] = (hb & 0xffffu) | (nb << 16);
    }

  // PV: M=16 t, N=64 d, K=256 kappa
  f32x4 oc[4];
#pragma unroll
  for (int j = 0; j < 4; ++j) oc[j] = (f32x4){0.f, 0.f, 0.f, 0.f};
  const f16* vpb = kpv + (size_t)NBH * KPROJ * DH + (size_t)bh * (DH * KPROJ);
#pragma unroll 2
  for (int kk = 0; kk < 8; ++kk) {
    f16x8 pa = *(const f16x8*)&Ps[w][l15][kk * 32 + quad * 8];
#pragma unroll
    for (int nd = 0; nd < 4; ++nd) {
      f16x8 bv = *(const f16x8*)(vpb + (size_t)(nd * 16 + l15) * KPROJ + kk * 32 + quad * 8);
      oc[nd] = __builtin_amdgcn_mfma_f32_16x16x32_f16(pa, bv, oc[nd], 0, 0, 0);
    }
  }

  // O -> LDS (reuse Ps[w]; wave-private, DS pipe is in-order within a wave)
  float rcp[4];
#pragma unroll
  for (int r = 0; r < 4; ++r) rcp[r] = 1.f / sm[r];
#pragma unroll
  for (int nd = 0; nd < 4; ++nd)
#pragma unroll
    for (int r = 0; r < 4; ++r) {
      f16 hh = (f16)(oc[nd][r] * rcp[r]);
      uint32_t hb = (uint32_t)__builtin_bit_cast(uint16_t, hh);
      uint32_t nb = (uint32_t)__shfl_xor((int)hb, 1);
      if (!(lane & 1))
        *(uint32_t*)&Ps[w][quad * 4 + r][nd * 16 + l15] = (hb & 0xffffu) | (nb << 16);
    }

  // coalesced store: lane covers 32B of a 128B output row chunk
  const int t_r = lane >> 2, ck2 = lane & 3;
  f16* orow = aout + ((size_t)(b * TB + t0b + w * 16 + t_r)) * NDIM + h * 64;
#pragma unroll
  for (int s = 0; s < 2; ++s) {
    uint4 v = *(const uint4*)&Ps[w][t_r][ck2 * 16 + s * 8];
    *(uint4*)(orow + ck2 * 16 + s * 8) = v;
  }
}

// ---------------------------------------------------------------------------
// Stage 5: Out = aout @ W0t^T  (M=16384, N=1024, K=1024) fp16 MFMA, fp32 out.
// ---------------------------------------------------------------------------
__launch_bounds__(256)
__global__ void k_out(const f16* __restrict__ A, const f16* __restrict__ Bt,
                      float* __restrict__ Out) {
  __shared__ __align__(16) f16 As[128 * 32];
  __shared__ __align__(16) f16 Bs[128 * 32];
  const int tid = threadIdx.x;
  const int w = tid >> 6, lane = tid & 63;
  const int quad = lane >> 4, l15 = lane & 15;
  const int bn0 = blockIdx.x * 128, bm0 = blockIdx.y * 128;
  const int wm = (w & 1) * 64, wn = (w >> 1) * 64;
  const int srow = lane >> 2, skc = lane & 3;

  f32x4 acc[4][4];
#pragma unroll
  for (int i = 0; i < 4; ++i)
#pragma unroll
    for (int j = 0; j < 4; ++j) acc[i][j] = (f32x4){0.f, 0.f, 0.f, 0.f};

  const f16* Ag0 = A + (size_t)(bm0 + w * 32 + srow) * NDIM + skc * 8;
  const f16* Bg0 = Bt + (size_t)(bn0 + w * 32 + srow) * NDIM + skc * 8;
  f16* Al0 = As + (w * 32) * 32;
  f16* Bl0 = Bs + (w * 32) * 32;

  for (int k0 = 0; k0 < NDIM; k0 += 32) {
    glds16(Ag0 + k0, Al0);
    glds16(Ag0 + (size_t)16 * NDIM + k0, Al0 + 16 * 32);
    glds16(Bg0 + k0, Bl0);
    glds16(Bg0 + (size_t)16 * NDIM + k0, Bl0 + 16 * 32);
    __syncthreads();
    f16x8 a[4], b[4];
#pragma unroll
    for (int i = 0; i < 4; ++i) a[i] = *(const f16x8*)(As + (wm + i * 16 + l15) * 32 + quad * 8);
#pragma unroll
    for (int j = 0; j < 4; ++j) b[j] = *(const f16x8*)(Bs + (wn + j * 16 + l15) * 32 + quad * 8);
#pragma unroll
    for (int i = 0; i < 4; ++i)
#pragma unroll
      for (int j = 0; j < 4; ++j)
        acc[i][j] = __builtin_amdgcn_mfma_f32_16x16x32_f16(a[i], b[j], acc[i][j], 0, 0, 0);
    __syncthreads();
  }

#pragma unroll
  for (int i = 0; i < 4; ++i) {
    int m = bm0 + wm + i * 16 + quad * 4;
#pragma unroll
    for (int j = 0; j < 4; ++j) {
      int n = bn0 + wn + j * 16 + l15;
#pragma unroll
      for (int r = 0; r < 4; ++r) Out[(size_t)(m + r) * NDIM + n] = acc[i][j][r];
    }
  }
}

// ---------------------------------------------------------------------------
extern "C" void kernel_launch(void* const* d_in, const int* in_sizes, int n_in,
                              void* d_out, int out_size, void* d_ws, size_t ws_size,
                              hipStream_t stream) {
  const float* X    = (const float*)d_in[0];  // [4,4096,1024]
  const float* P    = (const float*)d_in[1];  // [4096,256]
  const float* Wqkv = (const float*)d_in[2];  // [1024,3072]
  const float* W0   = (const float*)d_in[3];  // [1024,1024]
  float* Out = (float*)d_out;

  char* ws = (char*)d_ws;
  const size_t MB = 1ull << 20;
  f16* Xh   = (f16*)(ws);             // 32 MB (reused as aout after k_qkv)
  f16* aout = (f16*)(ws);
  f16* qt   = (f16*)(ws + 32 * MB);   // 32 MB  [bh][d][t]
  f16* kvt  = (f16*)(ws + 64 * MB);   // 64 MB  [r][bh][d][t]
  f16* kpv  = (f16*)(ws + 128 * MB);  // 4 MB   kp [bh][kap][d] + vpT [bh][d][kap]
  f16* Wqt  = (f16*)(ws + 132 * MB);  // 6 MB   [3072][1024]
  f16* W0t  = (f16*)(ws + 138 * MB);  // 2 MB   [1024][1024]
  f16* Ptb  = (f16*)(ws + 140 * MB);  // 2 MB   [256][4096]

  cvt_x<<<dim3(8192), 256, 0, stream>>>(X, Xh);
  cvt_t<<<dim3(48, 16), 256, 0, stream>>>(Wqkv, Wqt, 1024, 3072);
  cvt_t<<<dim3(16, 16), 256, 0, stream>>>(W0, W0t, 1024, 1024);
  cvt_t<<<dim3(4, 64), 256, 0, stream>>>(P, Ptb, 4096, 256);
  k_qkv<<<dim3(24, 128), 256, 0, stream>>>(Xh, Wqt, qt, kvt);
  k_proj<<<dim3(2, 64, 2), 256, 0, stream>>>(Ptb, kvt, kpv);
  k_attn<<<dim3(64, 64), 256, 0, stream>>>(qt, kpv, aout);
  k_out<<<dim3(8, 128), 256, 0, stream>>>(aout, W0t, Out);
}

// Round 6
// 664.432 us; speedup vs baseline: 1.0004x; 1.0004x over previous
//
#include <hip/hip_runtime.h>
#include <stdint.h>
#include <stddef.h>

#define TB    4096
#define NDIM  1024
#define NH    16
#define KPROJ 256
#define DH    64
#define NBH   64

typedef _Float16 f16;
typedef _Float16 f16x8 __attribute__((ext_vector_type(8)));
typedef float    f32x4 __attribute__((ext_vector_type(4)));

__device__ __forceinline__ void glds16(const f16* g, f16* l) {
  __builtin_amdgcn_global_load_lds((const __attribute__((address_space(1))) void*)g,
                                   (__attribute__((address_space(3))) void*)l, 16, 0, 0);
}

// ---------------------------------------------------------------------------
// fp32 -> fp16 elementwise (X)
// ---------------------------------------------------------------------------
__launch_bounds__(256)
__global__ void cvt_x(const float* __restrict__ in, f16* __restrict__ out) {
  size_t i = ((size_t)blockIdx.x * 256 + threadIdx.x) * 8;
  float4 v0 = *(const float4*)(in + i);
  float4 v1 = *(const float4*)(in + i + 4);
  union { f16 h[8]; uint4 u; } pk;
  pk.h[0] = (f16)v0.x; pk.h[1] = (f16)v0.y; pk.h[2] = (f16)v0.z; pk.h[3] = (f16)v0.w;
  pk.h[4] = (f16)v1.x; pk.h[5] = (f16)v1.y; pk.h[6] = (f16)v1.z; pk.h[7] = (f16)v1.w;
  *(uint4*)(out + i) = pk.u;
}

// ---------------------------------------------------------------------------
// fp32 [R][C] -> fp16 transposed [C][R]
// ---------------------------------------------------------------------------
__launch_bounds__(256)
__global__ void cvt_t(const float* __restrict__ in, f16* __restrict__ out, int R, int C) {
  __shared__ __align__(16) f16 s[64][72];
  const int tid = threadIdx.x;
  const int c0 = blockIdx.x * 64, r0 = blockIdx.y * 64;
#pragma unroll
  for (int it = 0; it < 4; ++it) {
    int chunk = it * 256 + tid;
    int r_l = chunk >> 4, c4 = (chunk & 15) * 4;
    float4 v = *(const float4*)(in + (size_t)(r0 + r_l) * C + c0 + c4);
    s[c4 + 0][r_l] = (f16)v.x; s[c4 + 1][r_l] = (f16)v.y;
    s[c4 + 2][r_l] = (f16)v.z; s[c4 + 3][r_l] = (f16)v.w;
  }
  __syncthreads();
#pragma unroll
  for (int it = 0; it < 2; ++it) {
    int chunk = it * 256 + tid;
    int c_l = chunk >> 3, rc = (chunk & 7) * 8;
    *(uint4*)(out + (size_t)(c0 + c_l) * R + r0 + rc) = *(const uint4*)&s[c_l][rc];
  }
}

// ---------------------------------------------------------------------------
// Stage 1: qkv = Xh @ Wt^T  (M=16384, N=3072, K=1024) fp16 MFMA, 128x128x32.
// Epilogue: C tile -> LDS [f][m] -> 16B full-sector stores into q/k/v [bh][d][t].
// ---------------------------------------------------------------------------
__launch_bounds__(256)
__global__ void k_qkv(const f16* __restrict__ Xh, const f16* __restrict__ Wt,
                      f16* __restrict__ qt, f16* __restrict__ kvt) {
  __shared__ __align__(16) f16 As[128 * 32];
  __shared__ __align__(16) f16 Bs[128 * 32];
  __shared__ __align__(16) f16 Cs[128][136];  // 34 KB, row=f local, col=m local
  const int tid = threadIdx.x;
  const int w = tid >> 6, lane = tid & 63;
  const int quad = lane >> 4, l15 = lane & 15;
  const int bn0 = blockIdx.x * 128, bm0 = blockIdx.y * 128;
  const int wm = (w & 1) * 64, wn = (w >> 1) * 64;
  const int srow = lane >> 2, skc = lane & 3;

  f32x4 acc[4][4];
#pragma unroll
  for (int i = 0; i < 4; ++i)
#pragma unroll
    for (int j = 0; j < 4; ++j) acc[i][j] = (f32x4){0.f, 0.f, 0.f, 0.f};

  const f16* Ag0 = Xh + (size_t)(bm0 + w * 32 + srow) * NDIM + skc * 8;
  const f16* Bg0 = Wt + (size_t)(bn0 + w * 32 + srow) * NDIM + skc * 8;
  f16* Al0 = As + (w * 32) * 32;
  f16* Bl0 = Bs + (w * 32) * 32;

  for (int k0 = 0; k0 < NDIM; k0 += 32) {
    glds16(Ag0 + k0, Al0);
    glds16(Ag0 + (size_t)16 * NDIM + k0, Al0 + 16 * 32);
    glds16(Bg0 + k0, Bl0);
    glds16(Bg0 + (size_t)16 * NDIM + k0, Bl0 + 16 * 32);
    __syncthreads();
    f16x8 a[4], b[4];
#pragma unroll
    for (int i = 0; i < 4; ++i) a[i] = *(const f16x8*)(As + (wm + i * 16 + l15) * 32 + quad * 8);
#pragma unroll
    for (int j = 0; j < 4; ++j) b[j] = *(const f16x8*)(Bs + (wn + j * 16 + l15) * 32 + quad * 8);
#pragma unroll
    for (int i = 0; i < 4; ++i)
#pragma unroll
      for (int j = 0; j < 4; ++j)
        acc[i][j] = __builtin_amdgcn_mfma_f32_16x16x32_f16(a[i], b[j], acc[i][j], 0, 0, 0);
    __syncthreads();
  }

  // C tile -> LDS [f][m] (4 consecutive m per 8B write)
#pragma unroll
  for (int i = 0; i < 4; ++i)
#pragma unroll
    for (int j = 0; j < 4; ++j) {
      union { f16 hh[4]; uint2 u; } pk;
#pragma unroll
      for (int r = 0; r < 4; ++r) pk.hh[r] = (f16)acc[i][j][r];
      *(uint2*)&Cs[wn + j * 16 + l15][wm + i * 16 + quad * 4] = pk.u;
    }
  __syncthreads();

  // each thread streams 64 m (=t) of one f row: 8 x 16B full-sector stores
  const int f_l = tid >> 1, mh = (tid & 1) * 64;
  const int f = bn0 + f_l;
  const int d = f / 48, rem = f - d * 48;
  const int rr = rem >> 4, h = rem & 15;
  f16* base = (rr == 0) ? qt : kvt + (size_t)(rr - 1) * ((size_t)NBH * DH * TB);
  const int bb = bm0 >> 12, tt0 = bm0 & 4095;
  f16* dst = base + ((size_t)((bb * NH + h) * DH + d)) * TB + tt0 + mh;
  const f16* srcp = &Cs[f_l][mh];
#pragma unroll
  for (int kx = 0; kx < 8; ++kx)
    *(uint4*)(dst + kx * 8) = *(const uint4*)(srcp + kx * 8);
}

// ---------------------------------------------------------------------------
// Stage 2: kp/vp = Pt @ kvt^T per (bh, r): M=128(kappa), N=64(d), K=4096(t).
// rv==0 (k): kp [bh][kappa][d];  rv==1 (v): vpT [bh][d][kappa].
// ---------------------------------------------------------------------------
__launch_bounds__(256)
__global__ void k_proj(const f16* __restrict__ Pt, const f16* __restrict__ kvt,
                       f16* __restrict__ kpv) {
  __shared__ __align__(16) f16 As[128 * 32];
  __shared__ __align__(16) f16 Bs[64 * 32];
  const int tid = threadIdx.x;
  const int w = tid >> 6, lane = tid & 63;
  const int quad = lane >> 4, l15 = lane & 15;
  const int km0 = blockIdx.x * 128;
  const int bh = blockIdx.y, rv = blockIdx.z;
  const int srow = lane >> 2, skc = lane & 3;
  const f16* Bbase = kvt + (size_t)(rv * NBH + bh) * DH * TB;  // [d][t]

  f32x4 acc[2][4];
#pragma unroll
  for (int i = 0; i < 2; ++i)
#pragma unroll
    for (int j = 0; j < 4; ++j) acc[i][j] = (f32x4){0.f, 0.f, 0.f, 0.f};

  const f16* Ag0 = Pt + (size_t)(km0 + w * 32 + srow) * TB + skc * 8;
  const f16* Bg0 = Bbase + (size_t)(w * 16 + srow) * TB + skc * 8;
  f16* Al0 = As + (w * 32) * 32;
  f16* Bl0 = Bs + (w * 16) * 32;

  for (int k0 = 0; k0 < TB; k0 += 32) {
    glds16(Ag0 + k0, Al0);
    glds16(Ag0 + (size_t)16 * TB + k0, Al0 + 16 * 32);
    glds16(Bg0 + k0, Bl0);
    __syncthreads();
    f16x8 a[2], b[4];
#pragma unroll
    for (int i = 0; i < 2; ++i) a[i] = *(const f16x8*)(As + (w * 32 + i * 16 + l15) * 32 + quad * 8);
#pragma unroll
    for (int j = 0; j < 4; ++j) b[j] = *(const f16x8*)(Bs + (j * 16 + l15) * 32 + quad * 8);
#pragma unroll
    for (int i = 0; i < 2; ++i)
#pragma unroll
      for (int j = 0; j < 4; ++j)
        acc[i][j] = __builtin_amdgcn_mfma_f32_16x16x32_f16(a[i], b[j], acc[i][j], 0, 0, 0);
    __syncthreads();
  }

  if (rv == 0) {
#pragma unroll
    for (int i = 0; i < 2; ++i) {
      int kap0 = km0 + w * 32 + i * 16 + quad * 4;
#pragma unroll
      for (int j = 0; j < 4; ++j) {
        int d = j * 16 + l15;
#pragma unroll
        for (int r = 0; r < 4; ++r)
          kpv[((size_t)bh * KPROJ + kap0 + r) * DH + d] = (f16)acc[i][j][r];
      }
    }
  } else {
    f16* vpT = kpv + (size_t)NBH * KPROJ * DH;
#pragma unroll
    for (int i = 0; i < 2; ++i) {
      int kap0 = km0 + w * 32 + i * 16 + quad * 4;
#pragma unroll
      for (int j = 0; j < 4; ++j) {
        int d = j * 16 + l15;
        union { f16 hh[4]; uint2 u; } pk;
#pragma unroll
        for (int r = 0; r < 4; ++r) pk.hh[r] = (f16)acc[i][j][r];
        *(uint2*)&vpT[((size_t)bh * DH + d) * KPROJ + kap0] = pk.u;
      }
    }
  }
}

// ---------------------------------------------------------------------------
// Stage 3+4: fused MFMA attention. grid (T/64, 64 bh), 4 waves; wave owns 16
// q-rows. __launch_bounds__(256,2): VGPR cap 256 so the 16x f32x4 score
// accumulators stay in registers (at (256) default the compiler capped at ~68
// VGPRs and spilled sc[] to scratch -> ~620 MB of hidden HBM traffic).
// ---------------------------------------------------------------------------
__launch_bounds__(256, 2)
__global__ void k_attn(const f16* __restrict__ qt, const f16* __restrict__ kpv,
                       f16* __restrict__ aout) {
  __shared__ __align__(16) f16 Ps[4][16][264];  // 33 KB (P staging, then O staging)
  __shared__ __align__(16) f16 Qs[64][72];      // 9 KB q tile transposed [t][d]
  const int tid = threadIdx.x;
  const int w = tid >> 6, lane = tid & 63;
  const int quad = lane >> 4, l15 = lane & 15;
  const int bh = blockIdx.y;
  const int t0b = blockIdx.x * 64;
  const int b = bh >> 4, h = bh & 15;

  {  // q tile: qt[bh][d][t0b..t0b+64) -> Qs[t][d]; 512 uint4 loads, 2/thread
#pragma unroll
    for (int it = 0; it < 2; ++it) {
      int idx = it * 256 + tid;
      int d_l = idx >> 3, ck = idx & 7;
      uint4 u = *(const uint4*)(qt + ((size_t)bh * DH + d_l) * TB + t0b + ck * 8);
      const f16* hp = (const f16*)&u;
#pragma unroll
      for (int e = 0; e < 8; ++e) Qs[ck * 8 + e][d_l] = hp[e];
    }
  }
  __syncthreads();

  f16x8 aq[2];
#pragma unroll
  for (int ks = 0; ks < 2; ++ks)
    aq[ks] = *(const f16x8*)&Qs[w * 16 + l15][ks * 32 + quad * 8];

  // S: 16 n-tiles of 16 kappa; B-frags from global (L2-resident)
  f32x4 sc[16];
  const f16* kpb = kpv + (size_t)bh * (KPROJ * DH);
#pragma unroll 4
  for (int nt = 0; nt < 16; ++nt) {
    f16x8 b0 = *(const f16x8*)(kpb + (size_t)(nt * 16 + l15) * DH + quad * 8);
    f16x8 b1 = *(const f16x8*)(kpb + (size_t)(nt * 16 + l15) * DH + 32 + quad * 8);
    f32x4 c = (f32x4){0.f, 0.f, 0.f, 0.f};
    c = __builtin_amdgcn_mfma_f32_16x16x32_f16(aq[0], b0, c, 0, 0, 0);
    c = __builtin_amdgcn_mfma_f32_16x16x32_f16(aq[1], b1, c, 0, 0, 0);
    sc[nt] = c;
  }

  // softmax: rows at quad*4+r, cols nt*16+l15
  float mx[4] = {-1e30f, -1e30f, -1e30f, -1e30f};
#pragma unroll
  for (int nt = 0; nt < 16; ++nt)
#pragma unroll
    for (int r = 0; r < 4; ++r) {
      float s = sc[nt][r] * 0.125f;
      sc[nt][r] = s;
      mx[r] = fmaxf(mx[r], s);
    }
#pragma unroll
  for (int r = 0; r < 4; ++r)
#pragma unroll
    for (int off = 1; off < 16; off <<= 1) mx[r] = fmaxf(mx[r], __shfl_xor(mx[r], off));
  float sm[4] = {0.f, 0.f, 0.f, 0.f};
#pragma unroll
  for (int nt = 0; nt < 16; ++nt)
#pragma unroll
    for (int r = 0; r < 4; ++r) {
      float e = __expf(sc[nt][r] - mx[r]);
      sc[nt][r] = e;
      sm[r] += e;
    }
#pragma unroll
  for (int r = 0; r < 4; ++r)
#pragma unroll
    for (int off = 1; off < 16; off <<= 1) sm[r] += __shfl_xor(sm[r], off);

  // P -> LDS (pack lane pairs -> b32, even lanes write)
#pragma unroll
  for (int nt = 0; nt < 16; ++nt)
#pragma unroll
    for (int r = 0; r < 4; ++r) {
      f16 hh = (f16)sc[nt][r];
      uint32_t hb = (uint32_t)__builtin_bit_cast(uint16_t, hh);
      uint32_t nb = (uint32_t)__shfl_xor((int)hb, 1);
      if (!(lane & 1))
        *(uint32_t*)&Ps[w][quad * 4 + r][nt * 16 + l15] = (hb & 0xffffu) | (nb << 16);
    }

  // PV: M=16 t, N=64 d, K=256 kappa
  f32x4 oc[4];
#pragma unroll
  for (int j = 0; j < 4; ++j) oc[j] = (f32x4){0.f, 0.f, 0.f, 0.f};
  const f16* vpb = kpv + (size_t)NBH * KPROJ * DH + (size_t)bh * (DH * KPROJ);
#pragma unroll 2
  for (int kk = 0; kk < 8; ++kk) {
    f16x8 pa = *(const f16x8*)&Ps[w][l15][kk * 32 + quad * 8];
#pragma unroll
    for (int nd = 0; nd < 4; ++nd) {
      f16x8 bv = *(const f16x8*)(vpb + (size_t)(nd * 16 + l15) * KPROJ + kk * 32 + quad * 8);
      oc[nd] = __builtin_amdgcn_mfma_f32_16x16x32_f16(pa, bv, oc[nd], 0, 0, 0);
    }
  }

  // O -> LDS (reuse Ps[w]; wave-private, DS pipe is in-order within a wave)
  float rcp[4];
#pragma unroll
  for (int r = 0; r < 4; ++r) rcp[r] = 1.f / sm[r];
#pragma unroll
  for (int nd = 0; nd < 4; ++nd)
#pragma unroll
    for (int r = 0; r < 4; ++r) {
      f16 hh = (f16)(oc[nd][r] * rcp[r]);
      uint32_t hb = (uint32_t)__builtin_bit_cast(uint16_t, hh);
      uint32_t nb = (uint32_t)__shfl_xor((int)hb, 1);
      if (!(lane & 1))
        *(uint32_t*)&Ps[w][quad * 4 + r][nd * 16 + l15] = (hb & 0xffffu) | (nb << 16);
    }

  // coalesced store: lane covers 32B of a 128B output row chunk
  const int t_r = lane >> 2, ck2 = lane & 3;
  f16* orow = aout + ((size_t)(b * TB + t0b + w * 16 + t_r)) * NDIM + h * 64;
#pragma unroll
  for (int s = 0; s < 2; ++s) {
    uint4 v = *(const uint4*)&Ps[w][t_r][ck2 * 16 + s * 8];
    *(uint4*)(orow + ck2 * 16 + s * 8) = v;
  }
}

// ---------------------------------------------------------------------------
// Stage 5: Out = aout @ W0t^T  (M=16384, N=1024, K=1024) fp16 MFMA, fp32 out.
// ---------------------------------------------------------------------------
__launch_bounds__(256)
__global__ void k_out(const f16* __restrict__ A, const f16* __restrict__ Bt,
                      float* __restrict__ Out) {
  __shared__ __align__(16) f16 As[128 * 32];
  __shared__ __align__(16) f16 Bs[128 * 32];
  const int tid = threadIdx.x;
  const int w = tid >> 6, lane = tid & 63;
  const int quad = lane >> 4, l15 = lane & 15;
  const int bn0 = blockIdx.x * 128, bm0 = blockIdx.y * 128;
  const int wm = (w & 1) * 64, wn = (w >> 1) * 64;
  const int srow = lane >> 2, skc = lane & 3;

  f32x4 acc[4][4];
#pragma unroll
  for (int i = 0; i < 4; ++i)
#pragma unroll
    for (int j = 0; j < 4; ++j) acc[i][j] = (f32x4){0.f, 0.f, 0.f, 0.f};

  const f16* Ag0 = A + (size_t)(bm0 + w * 32 + srow) * NDIM + skc * 8;
  const f16* Bg0 = Bt + (size_t)(bn0 + w * 32 + srow) * NDIM + skc * 8;
  f16* Al0 = As + (w * 32) * 32;
  f16* Bl0 = Bs + (w * 32) * 32;

  for (int k0 = 0; k0 < NDIM; k0 += 32) {
    glds16(Ag0 + k0, Al0);
    glds16(Ag0 + (size_t)16 * NDIM + k0, Al0 + 16 * 32);
    glds16(Bg0 + k0, Bl0);
    glds16(Bg0 + (size_t)16 * NDIM + k0, Bl0 + 16 * 32);
    __syncthreads();
    f16x8 a[4], b[4];
#pragma unroll
    for (int i = 0; i < 4; ++i) a[i] = *(const f16x8*)(As + (wm + i * 16 + l15) * 32 + quad * 8);
#pragma unroll
    for (int j = 0; j < 4; ++j) b[j] = *(const f16x8*)(Bs + (wn + j * 16 + l15) * 32 + quad * 8);
#pragma unroll
    for (int i = 0; i < 4; ++i)
#pragma unroll
      for (int j = 0; j < 4; ++j)
        acc[i][j] = __builtin_amdgcn_mfma_f32_16x16x32_f16(a[i], b[j], acc[i][j], 0, 0, 0);
    __syncthreads();
  }

#pragma unroll
  for (int i = 0; i < 4; ++i) {
    int m = bm0 + wm + i * 16 + quad * 4;
#pragma unroll
    for (int j = 0; j < 4; ++j) {
      int n = bn0 + wn + j * 16 + l15;
#pragma unroll
      for (int r = 0; r < 4; ++r) Out[(size_t)(m + r) * NDIM + n] = acc[i][j][r];
    }
  }
}

// ---------------------------------------------------------------------------
extern "C" void kernel_launch(void* const* d_in, const int* in_sizes, int n_in,
                              void* d_out, int out_size, void* d_ws, size_t ws_size,
                              hipStream_t stream) {
  const float* X    = (const float*)d_in[0];  // [4,4096,1024]
  const float* P    = (const float*)d_in[1];  // [4096,256]
  const float* Wqkv = (const float*)d_in[2];  // [1024,3072]
  const float* W0   = (const float*)d_in[3];  // [1024,1024]
  float* Out = (float*)d_out;

  char* ws = (char*)d_ws;
  const size_t MB = 1ull << 20;
  f16* Xh   = (f16*)(ws);             // 32 MB (reused as aout after k_qkv)
  f16* aout = (f16*)(ws);
  f16* qt   = (f16*)(ws + 32 * MB);   // 32 MB  [bh][d][t]
  f16* kvt  = (f16*)(ws + 64 * MB);   // 64 MB  [r][bh][d][t]
  f16* kpv  = (f16*)(ws + 128 * MB);  // 4 MB   kp [bh][kap][d] + vpT [bh][d][kap]
  f16* Wqt  = (f16*)(ws + 132 * MB);  // 6 MB   [3072][1024]
  f16* W0t  = (f16*)(ws + 138 * MB);  // 2 MB   [1024][1024]
  f16* Ptb  = (f16*)(ws + 140 * MB);  // 2 MB   [256][4096]

  cvt_x<<<dim3(8192), 256, 0, stream>>>(X, Xh);
  cvt_t<<<dim3(48, 16), 256, 0, stream>>>(Wqkv, Wqt, 1024, 3072);
  cvt_t<<<dim3(16, 16), 256, 0, stream>>>(W0, W0t, 1024, 1024);
  cvt_t<<<dim3(4, 64), 256, 0, stream>>>(P, Ptb, 4096, 256);
  k_qkv<<<dim3(24, 128), 256, 0, stream>>>(Xh, Wqt, qt, kvt);
  k_proj<<<dim3(2, 64, 2), 256, 0, stream>>>(Ptb, kvt, kpv);
  k_attn<<<dim3(64, 64), 256, 0, stream>>>(qt, kpv, aout);
  k_out<<<dim3(8, 128), 256, 0, stream>>>(aout, W0t, Out);
}